// Round 1
// baseline (1297.496 us; speedup 1.0000x reference)
//
#include <hip/hip_runtime.h>
#include <hip/hip_bf16.h>

#define HID 2048
#define NEXP 8
#define MINTER 1408
#define SINTER 5632
#define MTOK 4096
#define CAP 4096

#define BM 128
#define BN 128
#define BK 64
#define LDK 72   // padded LDS row stride in bf16 elements (144 B)

typedef short bf16x8 __attribute__((ext_vector_type(8)));
typedef float floatx4 __attribute__((ext_vector_type(4)));

__device__ __forceinline__ unsigned short f2bf_rn(float f) {
    union { float f; unsigned u; } v; v.f = f;
    unsigned r = v.u + 0x7FFFu + ((v.u >> 16) & 1u);
    return (unsigned short)(r >> 16);
}

__device__ __forceinline__ unsigned pack_bf16x2(float a, float b) {
    __hip_bfloat162 h = __float22bfloat162_rn(make_float2(a, b));
    unsigned u;
    __builtin_memcpy(&u, &h, 4);
    return u;
}

// ---------------- x -> bf16 cast ----------------
__global__ void cvt_kernel(const float* __restrict__ x, unsigned short* __restrict__ xb) {
    int i = (blockIdx.x * 256 + threadIdx.x) * 4;
    float4 v = *(const float4*)(x + i);
    uint2 pk;
    pk.x = pack_bf16x2(v.x, v.y);
    pk.y = pack_bf16x2(v.z, v.w);
    *(uint2*)(xb + i) = pk;
}

// ---------------- router + shared gate ----------------
__global__ void router_kernel(const float* __restrict__ x, const float* __restrict__ gw,
                              const float* __restrict__ sgw,
                              float* __restrict__ tok2w, float* __restrict__ gate_sig,
                              int* __restrict__ counts, int* __restrict__ tok_list) {
    int wid = threadIdx.x >> 6, lane = threadIdx.x & 63;
    int tok = blockIdx.x * 4 + wid;
    const float* xr = x + (size_t)tok * HID;
    float acc[9];
#pragma unroll
    for (int e = 0; e < 9; e++) acc[e] = 0.f;
    for (int i = lane; i < HID; i += 64) {
        float xv = xr[i];
#pragma unroll
        for (int e = 0; e < NEXP; e++) acc[e] += xv * gw[e * HID + i];
        acc[8] += xv * sgw[i];
    }
#pragma unroll
    for (int e = 0; e < 9; e++) {
#pragma unroll
        for (int off = 32; off; off >>= 1) acc[e] += __shfl_down(acc[e], off);
    }
    if (lane == 0) {
        float m = acc[0];
#pragma unroll
        for (int e = 1; e < NEXP; e++) m = fmaxf(m, acc[e]);
        float ex[NEXP]; float s = 0.f;
#pragma unroll
        for (int e = 0; e < NEXP; e++) { ex[e] = __expf(acc[e] - m); s += ex[e]; }
        int e1 = 0; float b1 = ex[0];
#pragma unroll
        for (int e = 1; e < NEXP; e++) if (ex[e] > b1) { b1 = ex[e]; e1 = e; }
        int e2 = -1; float b2 = -1.f;
#pragma unroll
        for (int e = 0; e < NEXP; e++) {
            if (e == e1) continue;
            if (ex[e] > b2) { b2 = ex[e]; e2 = e; }
        }
        float inv = 1.f / s;
        int p = atomicAdd(&counts[e1], 1);
        tok_list[e1 * CAP + p] = tok * 2;
        tok2w[tok * 2] = b1 * inv;
        p = atomicAdd(&counts[e2], 1);
        tok_list[e2 * CAP + p] = tok * 2 + 1;
        tok2w[tok * 2 + 1] = b2 * inv;
        gate_sig[tok] = 1.f / (1.f + __expf(-acc[8]));
    }
}

// ---------------- generic NT GEMM, bf16 MFMA ----------------
// MODE 0: shared gate_up, dual halves + silu*mul -> bf16 s_inter     (KDIM=2048)
// MODE 1: moe w13, gathered rows, dual + silu*mul -> bf16 moe_inter  (KDIM=2048)
// MODE 2: shared down, * sigmoid gate -> fp32 store to d_out         (KDIM=5632)
// MODE 3: moe w2, gathered, * routing weight -> atomicAdd to d_out   (KDIM=1408)
template <int KDIM, int MODE>
__global__ __launch_bounds__(256, 2) void gemm_kernel(
    const unsigned short* __restrict__ A, const float* __restrict__ B,
    void* __restrict__ outp, const int* __restrict__ tok_list,
    const int* __restrict__ counts, const float* __restrict__ tok2w,
    const float* __restrict__ gate_sig)
{
    constexpr bool DUAL = (MODE == 0 || MODE == 1);
    constexpr bool GATHER = (MODE == 1 || MODE == 3);
    constexpr int NHALF = (MODE == 0) ? SINTER : (MODE == 1) ? MINTER : HID;

    extern __shared__ unsigned short smem[];
    unsigned short* lA = smem;
    unsigned short* lBg = smem + BM * LDK;
    unsigned short* lBu = lBg + (DUAL ? BM * LDK : 0);

    const int e = GATHER ? blockIdx.z : 0;
    int cnt = 0;
    const int r0 = blockIdx.y * BM;
    if constexpr (GATHER) {
        cnt = counts[e];
        if (r0 >= cnt) return;
    }
    const int bn0 = blockIdx.x * BN;
    const int tid = threadIdx.x;

    const float* Bbase = B;
    if constexpr (MODE == 1) Bbase += (size_t)e * (2 * MINTER) * HID;
    if constexpr (MODE == 3) Bbase += (size_t)e * HID * MINTER;

    // per-thread A staging descriptors (4 x 16B chunks per K-tile)
    const unsigned short* aptr[4];
    int la_off[4];
#pragma unroll
    for (int i = 0; i < 4; i++) {
        int c = tid + i * 256;
        int r = c >> 3, cc = c & 7;
        int gr;
        if constexpr (GATHER) {
            int idx = min(r0 + r, cnt - 1);
            int entry = tok_list[e * CAP + idx];
            gr = (MODE == 1) ? (entry >> 1) : entry;
        } else {
            gr = r0 + r;
        }
        aptr[i] = A + (size_t)gr * KDIM + cc * 8;
        la_off[i] = r * LDK + cc * 8;
    }
    // per-thread B staging descriptors (8 x float4 per half per K-tile)
    const float* bptr[8];
    int lb_off[8];
#pragma unroll
    for (int j = 0; j < 8; j++) {
        int c = tid + j * 256;
        int r = c >> 4, cc = c & 15;
        bptr[j] = Bbase + (size_t)(bn0 + r) * KDIM + cc * 4;
        lb_off[j] = r * LDK + cc * 4;
    }

    const int lane = tid & 63, wid = tid >> 6;
    const int wr = (wid >> 1) * 64, wc = (wid & 1) * 64;
    const int m16 = lane & 15, quad = lane >> 4;
    const int a_base = (wr + m16) * LDK + quad * 8;
    const int b_base = (wc + m16) * LDK + quad * 8;

    floatx4 accG[4][4];
    floatx4 accU[4][4];
#pragma unroll
    for (int i = 0; i < 4; i++)
#pragma unroll
        for (int j = 0; j < 4; j++) {
            accG[i][j] = floatx4{0.f, 0.f, 0.f, 0.f};
            if constexpr (DUAL) accU[i][j] = floatx4{0.f, 0.f, 0.f, 0.f};
        }

    const int KT = KDIM / BK;
    for (int kt = 0; kt < KT; kt++) {
        const int k0 = kt * BK;
#pragma unroll
        for (int i = 0; i < 4; i++)
            *(uint4*)(lA + la_off[i]) = *(const uint4*)(aptr[i] + k0);
#pragma unroll
        for (int j = 0; j < 8; j++) {
            float4 f = *(const float4*)(bptr[j] + k0);
            uint2 pk;
            pk.x = pack_bf16x2(f.x, f.y);
            pk.y = pack_bf16x2(f.z, f.w);
            *(uint2*)(lBg + lb_off[j]) = pk;
        }
        if constexpr (DUAL) {
#pragma unroll
            for (int j = 0; j < 8; j++) {
                float4 f = *(const float4*)(bptr[j] + (size_t)NHALF * KDIM + k0);
                uint2 pk;
                pk.x = pack_bf16x2(f.x, f.y);
                pk.y = pack_bf16x2(f.z, f.w);
                *(uint2*)(lBu + lb_off[j]) = pk;
            }
        }
        __syncthreads();
#pragma unroll
        for (int kk = 0; kk < 2; kk++) {
            bf16x8 af[4], bg[4];
#pragma unroll
            for (int t = 0; t < 4; t++)
                af[t] = *(const bf16x8*)(lA + a_base + t * 16 * LDK + kk * 32);
#pragma unroll
            for (int t = 0; t < 4; t++)
                bg[t] = *(const bf16x8*)(lBg + b_base + t * 16 * LDK + kk * 32);
#pragma unroll
            for (int mt = 0; mt < 4; mt++)
#pragma unroll
                for (int nt = 0; nt < 4; nt++)
                    accG[mt][nt] = __builtin_amdgcn_mfma_f32_16x16x32_bf16(
                        af[mt], bg[nt], accG[mt][nt], 0, 0, 0);
            if constexpr (DUAL) {
                bf16x8 bu[4];
#pragma unroll
                for (int t = 0; t < 4; t++)
                    bu[t] = *(const bf16x8*)(lBu + b_base + t * 16 * LDK + kk * 32);
#pragma unroll
                for (int mt = 0; mt < 4; mt++)
#pragma unroll
                    for (int nt = 0; nt < 4; nt++)
                        accU[mt][nt] = __builtin_amdgcn_mfma_f32_16x16x32_bf16(
                            af[mt], bu[nt], accU[mt][nt], 0, 0, 0);
            }
        }
        __syncthreads();
    }

    // ---------------- epilogues ----------------
    if constexpr (MODE == 0) {
        unsigned short* sout = (unsigned short*)outp;
#pragma unroll
        for (int mt = 0; mt < 4; mt++) {
#pragma unroll
            for (int nt = 0; nt < 4; nt++) {
                int col = bn0 + wc + nt * 16 + m16;
#pragma unroll
                for (int r = 0; r < 4; r++) {
                    int row = r0 + wr + mt * 16 + quad * 4 + r;
                    float g = accG[mt][nt][r], u = accU[mt][nt][r];
                    float s = g / (1.f + __expf(-g)) * u;
                    sout[(size_t)row * SINTER + col] = f2bf_rn(s);
                }
            }
        }
    } else if constexpr (MODE == 1) {
        unsigned short* sout = (unsigned short*)outp;
#pragma unroll
        for (int mt = 0; mt < 4; mt++) {
            int ent[4]; bool val[4];
#pragma unroll
            for (int r = 0; r < 4; r++) {
                int idx = r0 + wr + mt * 16 + quad * 4 + r;
                val[r] = idx < cnt;
                ent[r] = val[r] ? tok_list[e * CAP + idx] : 0;
            }
#pragma unroll
            for (int nt = 0; nt < 4; nt++) {
                int col = bn0 + wc + nt * 16 + m16;
#pragma unroll
                for (int r = 0; r < 4; r++) {
                    if (val[r]) {
                        float g = accG[mt][nt][r], u = accU[mt][nt][r];
                        float s = g / (1.f + __expf(-g)) * u;
                        sout[(size_t)ent[r] * MINTER + col] = f2bf_rn(s);
                    }
                }
            }
        }
    } else if constexpr (MODE == 2) {
        float* fout = (float*)outp;
#pragma unroll
        for (int mt = 0; mt < 4; mt++) {
            int rowv[4]; float gs[4];
#pragma unroll
            for (int r = 0; r < 4; r++) {
                rowv[r] = r0 + wr + mt * 16 + quad * 4 + r;
                gs[r] = gate_sig[rowv[r]];
            }
#pragma unroll
            for (int nt = 0; nt < 4; nt++) {
                int col = bn0 + wc + nt * 16 + m16;
#pragma unroll
                for (int r = 0; r < 4; r++)
                    fout[(size_t)rowv[r] * HID + col] = accG[mt][nt][r] * gs[r];
            }
        }
    } else {
        float* fout = (float*)outp;
#pragma unroll
        for (int mt = 0; mt < 4; mt++) {
            int tokv[4]; float wv[4]; bool val[4];
#pragma unroll
            for (int r = 0; r < 4; r++) {
                int idx = r0 + wr + mt * 16 + quad * 4 + r;
                val[r] = idx < cnt;
                if (val[r]) {
                    int ent = tok_list[e * CAP + idx];
                    tokv[r] = ent >> 1;
                    wv[r] = tok2w[ent];
                } else { tokv[r] = 0; wv[r] = 0.f; }
            }
#pragma unroll
            for (int nt = 0; nt < 4; nt++) {
                int col = bn0 + wc + nt * 16 + m16;
#pragma unroll
                for (int r = 0; r < 4; r++) {
                    if (val[r])
                        unsafeAtomicAdd(&fout[(size_t)tokv[r] * HID + col],
                                        accG[mt][nt][r] * wv[r]);
                }
            }
        }
    }
}

extern "C" void kernel_launch(void* const* d_in, const int* in_sizes, int n_in,
                              void* d_out, int out_size, void* d_ws, size_t ws_size,
                              hipStream_t stream) {
    const float* x    = (const float*)d_in[0];
    const float* gw   = (const float*)d_in[1];
    const float* sgw  = (const float*)d_in[2];
    const float* sgup = (const float*)d_in[3];
    const float* sdwn = (const float*)d_in[4];
    const float* w13  = (const float*)d_in[5];
    const float* w2   = (const float*)d_in[6];
    float* out = (float*)d_out;

    char* p = (char*)d_ws;
    unsigned short* xb = (unsigned short*)p;        p += (size_t)MTOK * HID * 2;
    unsigned short* s_inter = (unsigned short*)p;   p += (size_t)MTOK * SINTER * 2;
    unsigned short* moe_inter = (unsigned short*)p; p += (size_t)MTOK * 2 * MINTER * 2;
    float* tok2w = (float*)p;                       p += (size_t)MTOK * 2 * 4;
    float* gate_sig = (float*)p;                    p += (size_t)MTOK * 4;
    int* tok_list = (int*)p;                        p += (size_t)NEXP * CAP * 4;
    int* counts = (int*)p;                          p += 64;

    hipMemsetAsync(counts, 0, NEXP * sizeof(int), stream);

    cvt_kernel<<<(MTOK * HID) / 1024, 256, 0, stream>>>(x, xb);
    router_kernel<<<MTOK / 4, 256, 0, stream>>>(x, gw, sgw, tok2w, gate_sig, counts, tok_list);

    const size_t lds_dual = 3 * BM * LDK * sizeof(unsigned short);   // 55296 B
    const size_t lds_single = 2 * BM * LDK * sizeof(unsigned short); // 36864 B

    // shared expert gate_up + silu*mul -> s_inter
    gemm_kernel<HID, 0><<<dim3(SINTER / BN, MTOK / BM), 256, lds_dual, stream>>>(
        xb, sgup, s_inter, nullptr, nullptr, nullptr, nullptr);
    // moe w13 + silu*mul -> moe_inter (gathered)
    gemm_kernel<HID, 1><<<dim3(MINTER / BN, CAP / BM, NEXP), 256, lds_dual, stream>>>(
        xb, w13, moe_inter, tok_list, counts, nullptr, nullptr);
    // shared down * sigmoid(gate) -> d_out (full store)
    gemm_kernel<SINTER, 2><<<dim3(HID / BN, MTOK / BM), 256, lds_single, stream>>>(
        s_inter, sdwn, out, nullptr, nullptr, nullptr, gate_sig);
    // moe w2 * routing weight -> atomicAdd into d_out
    gemm_kernel<MINTER, 3><<<dim3(HID / BN, CAP / BM, NEXP), 256, lds_single, stream>>>(
        moe_inter, w2, out, tok_list, counts, tok2w, nullptr);
}

// Round 2
// 1101.662 us; speedup vs baseline: 1.1778x; 1.1778x over previous
//
#include <hip/hip_runtime.h>
#include <hip/hip_bf16.h>

#define HID 2048
#define NEXP 8
#define MINTER 1408
#define SINTER 5632
#define MTOK 4096
#define CAP 4096

#define BM 128
#define BN 128
#define BK 64

typedef short bf16x8 __attribute__((ext_vector_type(8)));
typedef float floatx4 __attribute__((ext_vector_type(4)));

__device__ __forceinline__ unsigned short f2bf_rn(float f) {
    union { float f; unsigned u; } v; v.f = f;
    unsigned r = v.u + 0x7FFFu + ((v.u >> 16) & 1u);
    return (unsigned short)(r >> 16);
}

__device__ __forceinline__ unsigned pack_bf16x2(float a, float b) {
    __hip_bfloat162 h = __float22bfloat162_rn(make_float2(a, b));
    unsigned u;
    __builtin_memcpy(&u, &h, 4);
    return u;
}

// async global->LDS, 16B per lane; lds dest must be wave-uniform base (+lane*16 by HW)
__device__ __forceinline__ void async16(const unsigned short* g, unsigned short* l) {
    __builtin_amdgcn_global_load_lds(
        (const __attribute__((address_space(1))) unsigned int*)(g),
        (__attribute__((address_space(3))) unsigned int*)(l),
        16, 0, 0);
}

// ---------------- fp32 -> bf16 cast (grid: n/1024 blocks) ----------------
__global__ void cvt_kernel(const float* __restrict__ x, unsigned short* __restrict__ xb) {
    int i = (blockIdx.x * 256 + threadIdx.x) * 4;
    float4 v = *(const float4*)(x + i);
    uint2 pk;
    pk.x = pack_bf16x2(v.x, v.y);
    pk.y = pack_bf16x2(v.z, v.w);
    *(uint2*)(xb + i) = pk;
}

// ---------------- router + shared gate ----------------
__global__ void router_kernel(const float* __restrict__ x, const float* __restrict__ gw,
                              const float* __restrict__ sgw,
                              float* __restrict__ tok2w, float* __restrict__ gate_sig,
                              int* __restrict__ counts, int* __restrict__ tok_list) {
    int wid = threadIdx.x >> 6, lane = threadIdx.x & 63;
    int tok = blockIdx.x * 4 + wid;
    const float* xr = x + (size_t)tok * HID;
    float acc[9];
#pragma unroll
    for (int e = 0; e < 9; e++) acc[e] = 0.f;
    for (int i = lane; i < HID; i += 64) {
        float xv = xr[i];
#pragma unroll
        for (int e = 0; e < NEXP; e++) acc[e] += xv * gw[e * HID + i];
        acc[8] += xv * sgw[i];
    }
#pragma unroll
    for (int e = 0; e < 9; e++) {
#pragma unroll
        for (int off = 32; off; off >>= 1) acc[e] += __shfl_down(acc[e], off);
    }
    if (lane == 0) {
        float m = acc[0];
#pragma unroll
        for (int e = 1; e < NEXP; e++) m = fmaxf(m, acc[e]);
        float ex[NEXP]; float s = 0.f;
#pragma unroll
        for (int e = 0; e < NEXP; e++) { ex[e] = __expf(acc[e] - m); s += ex[e]; }
        int e1 = 0; float b1 = ex[0];
#pragma unroll
        for (int e = 1; e < NEXP; e++) if (ex[e] > b1) { b1 = ex[e]; e1 = e; }
        int e2 = -1; float b2 = -1.f;
#pragma unroll
        for (int e = 0; e < NEXP; e++) {
            if (e == e1) continue;
            if (ex[e] > b2) { b2 = ex[e]; e2 = e; }
        }
        float inv = 1.f / s;
        int p = atomicAdd(&counts[e1], 1);
        tok_list[e1 * CAP + p] = tok * 2;
        tok2w[tok * 2] = b1 * inv;
        p = atomicAdd(&counts[e2], 1);
        tok_list[e2 * CAP + p] = tok * 2 + 1;
        tok2w[tok * 2 + 1] = b2 * inv;
        gate_sig[tok] = 1.f / (1.f + __expf(-acc[8]));
    }
}

// ---------------- generic NT GEMM, bf16 MFMA, global_load_lds + XOR swizzle ----
// MODE 0: shared gate_up, dual halves + silu*mul -> bf16 s_inter     (KDIM=2048)
// MODE 1: moe w13, gathered rows, dual + silu*mul -> bf16 moe_inter  (KDIM=2048)
// MODE 2: shared down, * sigmoid gate -> fp32 store to d_out         (KDIM=5632)
// MODE 3: moe w2, gathered, * routing weight -> atomicAdd to d_out   (KDIM=1408)
// LDS layout per tile: row-major 128 rows x 64 k (bf16), 128 B/row, NO pad;
// chunk (16B) position within row is XOR-swizzled by (row & 7).
template <int KDIM, int MODE>
__global__ __launch_bounds__(256, 2) void gemm_kernel(
    const unsigned short* __restrict__ A, const unsigned short* __restrict__ B,
    void* __restrict__ outp, const int* __restrict__ tok_list,
    const int* __restrict__ counts, const float* __restrict__ tok2w,
    const float* __restrict__ gate_sig)
{
    constexpr bool DUAL = (MODE == 0 || MODE == 1);
    constexpr bool GATHER = (MODE == 1 || MODE == 3);
    constexpr int NHALF = (MODE == 0) ? SINTER : (MODE == 1) ? MINTER : HID;

    extern __shared__ unsigned short smem[];
    unsigned short* lA = smem;                 // 128*64 bf16 = 16 KB
    unsigned short* lBg = smem + BM * BK;      // 16 KB
    unsigned short* lBu = lBg + (DUAL ? BN * BK : 0);

    const int e = GATHER ? blockIdx.z : 0;
    int cnt = 0;
    const int r0 = blockIdx.y * BM;
    if constexpr (GATHER) {
        cnt = counts[e];
        if (r0 >= cnt) return;
    }
    const int bn0 = blockIdx.x * BN;
    const int tid = threadIdx.x;
    const int lane = tid & 63, wid = tid >> 6;

    const unsigned short* Bbase = B;
    if constexpr (MODE == 1) Bbase += (size_t)e * (2 * MINTER) * HID;
    if constexpr (MODE == 3) Bbase += (size_t)e * HID * MINTER;

    // staging: per wave-call, 64 lanes load 8 rows x 8 chunks (16B). lane = r8*8+ch.
    // LDS chunk position ch holds global chunk (ch ^ r8)  -> read-side swizzle (c ^ (row&7)).
    const int r8 = lane >> 3, ch = lane & 7;
    const int swz = (ch ^ r8) * 8;   // global element offset of this lane's chunk

    const unsigned short* gA[4];
    unsigned short* dA[4];
    const unsigned short* gB[4];
    unsigned short* dB[4];
#pragma unroll
    for (int j = 0; j < 4; j++) {
        const int rrow = wid * 32 + j * 8;          // call base row within tile
        int grow;
        if constexpr (GATHER) {
            int idx = min(r0 + rrow + r8, cnt - 1);
            int entry = tok_list[e * CAP + idx];
            grow = (MODE == 1) ? (entry >> 1) : entry;
        } else {
            grow = r0 + rrow + r8;
        }
        gA[j] = A + (size_t)grow * KDIM + swz;
        dA[j] = lA + rrow * BK;                     // wave-uniform
        gB[j] = Bbase + (size_t)(bn0 + rrow + r8) * KDIM + swz;
        dB[j] = lBg + rrow * BK;
    }

    const int m16 = lane & 15, quad = lane >> 4;
    const int m7 = m16 & 7;
    const int wr = (wid >> 1) * 64, wc = (wid & 1) * 64;
    const int aBase = (wr + m16) * BK;
    const int bBase = (wc + m16) * BK;

    floatx4 accG[4][4];
    floatx4 accU[4][4];
#pragma unroll
    for (int i = 0; i < 4; i++)
#pragma unroll
        for (int j = 0; j < 4; j++) {
            accG[i][j] = floatx4{0.f, 0.f, 0.f, 0.f};
            if constexpr (DUAL) accU[i][j] = floatx4{0.f, 0.f, 0.f, 0.f};
        }

    const int KT = KDIM / BK;
    for (int kt = 0; kt < KT; kt++) {
#pragma unroll
        for (int j = 0; j < 4; j++) { async16(gA[j], dA[j]); gA[j] += BK; }
#pragma unroll
        for (int j = 0; j < 4; j++) { async16(gB[j], dB[j]); gB[j] += BK; }
        if constexpr (DUAL) {
#pragma unroll
            for (int j = 0; j < 4; j++) {
                async16(gB[j] + ((size_t)NHALF * KDIM - BK), dB[j] + BN * BK);
            }
        }
        __syncthreads();   // drains vmcnt -> LDS tiles complete
#pragma unroll
        for (int kk = 0; kk < 2; kk++) {
            const int so = ((kk * 4 + quad) ^ m7) * 8;   // swizzled chunk offset
            bf16x8 af[4], bg[4];
#pragma unroll
            for (int t = 0; t < 4; t++)
                af[t] = *(const bf16x8*)(lA + aBase + t * 16 * BK + so);
#pragma unroll
            for (int t = 0; t < 4; t++)
                bg[t] = *(const bf16x8*)(lBg + bBase + t * 16 * BK + so);
#pragma unroll
            for (int mt = 0; mt < 4; mt++)
#pragma unroll
                for (int nt = 0; nt < 4; nt++)
                    accG[mt][nt] = __builtin_amdgcn_mfma_f32_16x16x32_bf16(
                        af[mt], bg[nt], accG[mt][nt], 0, 0, 0);
            if constexpr (DUAL) {
                bf16x8 bu[4];
#pragma unroll
                for (int t = 0; t < 4; t++)
                    bu[t] = *(const bf16x8*)(lBu + bBase + t * 16 * BK + so);
#pragma unroll
                for (int mt = 0; mt < 4; mt++)
#pragma unroll
                    for (int nt = 0; nt < 4; nt++)
                        accU[mt][nt] = __builtin_amdgcn_mfma_f32_16x16x32_bf16(
                            af[mt], bu[nt], accU[mt][nt], 0, 0, 0);
            }
        }
        __syncthreads();
    }

    // ---------------- epilogues ----------------
    if constexpr (MODE == 0) {
        unsigned short* sout = (unsigned short*)outp;
#pragma unroll
        for (int mt = 0; mt < 4; mt++) {
#pragma unroll
            for (int nt = 0; nt < 4; nt++) {
                int col = bn0 + wc + nt * 16 + m16;
#pragma unroll
                for (int r = 0; r < 4; r++) {
                    int row = r0 + wr + mt * 16 + quad * 4 + r;
                    float g = accG[mt][nt][r], u = accU[mt][nt][r];
                    float s = g / (1.f + __expf(-g)) * u;
                    sout[(size_t)row * SINTER + col] = f2bf_rn(s);
                }
            }
        }
    } else if constexpr (MODE == 1) {
        unsigned short* sout = (unsigned short*)outp;
#pragma unroll
        for (int mt = 0; mt < 4; mt++) {
            int ent[4]; bool val[4];
#pragma unroll
            for (int r = 0; r < 4; r++) {
                int idx = r0 + wr + mt * 16 + quad * 4 + r;
                val[r] = idx < cnt;
                ent[r] = val[r] ? tok_list[e * CAP + idx] : 0;
            }
#pragma unroll
            for (int nt = 0; nt < 4; nt++) {
                int col = bn0 + wc + nt * 16 + m16;
#pragma unroll
                for (int r = 0; r < 4; r++) {
                    if (val[r]) {
                        float g = accG[mt][nt][r], u = accU[mt][nt][r];
                        float s = g / (1.f + __expf(-g)) * u;
                        sout[(size_t)ent[r] * MINTER + col] = f2bf_rn(s);
                    }
                }
            }
        }
    } else if constexpr (MODE == 2) {
        float* fout = (float*)outp;
#pragma unroll
        for (int mt = 0; mt < 4; mt++) {
            int rowv[4]; float gs[4];
#pragma unroll
            for (int r = 0; r < 4; r++) {
                rowv[r] = r0 + wr + mt * 16 + quad * 4 + r;
                gs[r] = gate_sig[rowv[r]];
            }
#pragma unroll
            for (int nt = 0; nt < 4; nt++) {
                int col = bn0 + wc + nt * 16 + m16;
#pragma unroll
                for (int r = 0; r < 4; r++)
                    fout[(size_t)rowv[r] * HID + col] = accG[mt][nt][r] * gs[r];
            }
        }
    } else {
        float* fout = (float*)outp;
#pragma unroll
        for (int mt = 0; mt < 4; mt++) {
            int tokv[4]; float wv[4]; bool val[4];
#pragma unroll
            for (int r = 0; r < 4; r++) {
                int idx = r0 + wr + mt * 16 + quad * 4 + r;
                val[r] = idx < cnt;
                if (val[r]) {
                    int ent = tok_list[e * CAP + idx];
                    tokv[r] = ent >> 1;
                    wv[r] = tok2w[ent];
                } else { tokv[r] = 0; wv[r] = 0.f; }
            }
#pragma unroll
            for (int nt = 0; nt < 4; nt++) {
                int col = bn0 + wc + nt * 16 + m16;
#pragma unroll
                for (int r = 0; r < 4; r++) {
                    if (val[r])
                        unsafeAtomicAdd(&fout[(size_t)tokv[r] * HID + col],
                                        accG[mt][nt][r] * wv[r]);
                }
            }
        }
    }
}

extern "C" void kernel_launch(void* const* d_in, const int* in_sizes, int n_in,
                              void* d_out, int out_size, void* d_ws, size_t ws_size,
                              hipStream_t stream) {
    const float* x    = (const float*)d_in[0];
    const float* gw   = (const float*)d_in[1];
    const float* sgw  = (const float*)d_in[2];
    const float* sgup = (const float*)d_in[3];
    const float* sdwn = (const float*)d_in[4];
    const float* w13  = (const float*)d_in[5];
    const float* w2   = (const float*)d_in[6];
    float* out = (float*)d_out;

    const size_t N_SGUP = (size_t)2 * SINTER * HID;   // 23,068,672
    const size_t N_SDWN = (size_t)HID * SINTER;       // 11,534,336
    const size_t N_W13  = (size_t)NEXP * 2 * MINTER * HID; // 46,137,344
    const size_t N_W2   = (size_t)NEXP * HID * MINTER;     // 23,068,672

    char* p = (char*)d_ws;
    unsigned short* xb = (unsigned short*)p;     p += (size_t)MTOK * HID * 2;        // 16 MB
    unsigned short* inter = (unsigned short*)p;  p += (size_t)MTOK * SINTER * 2;     // 46 MB (union)
    unsigned short* wbuf = (unsigned short*)p;   p += (N_W13 + N_W2) * 2;            // 138 MB (union)
    float* tok2w = (float*)p;                    p += (size_t)MTOK * 2 * 4;
    float* gate_sig = (float*)p;                 p += (size_t)MTOK * 4;
    int* tok_list = (int*)p;                     p += (size_t)NEXP * CAP * 4;
    int* counts = (int*)p;                       p += 64;

    // phase A weight views (overwritten in phase B after shared expert is done)
    unsigned short* sgup_b = wbuf;
    unsigned short* sdwn_b = wbuf + N_SGUP;
    // phase B weight views
    unsigned short* w13_b = wbuf;
    unsigned short* w2_b  = wbuf + N_W13;

    hipMemsetAsync(counts, 0, NEXP * sizeof(int), stream);

    cvt_kernel<<<(MTOK * HID) / 1024, 256, 0, stream>>>(x, xb);
    router_kernel<<<MTOK / 4, 256, 0, stream>>>(x, gw, sgw, tok2w, gate_sig, counts, tok_list);

    const size_t lds_dual = 3 * BM * BK * sizeof(unsigned short);   // 48 KB
    const size_t lds_single = 2 * BM * BK * sizeof(unsigned short); // 32 KB

    // ---- shared expert ----
    cvt_kernel<<<N_SGUP / 1024, 256, 0, stream>>>(sgup, sgup_b);
    cvt_kernel<<<N_SDWN / 1024, 256, 0, stream>>>(sdwn, sdwn_b);
    gemm_kernel<HID, 0><<<dim3(SINTER / BN, MTOK / BM), 256, lds_dual, stream>>>(
        xb, sgup_b, inter, nullptr, nullptr, nullptr, nullptr);
    gemm_kernel<SINTER, 2><<<dim3(HID / BN, MTOK / BM), 256, lds_single, stream>>>(
        inter, sdwn_b, out, nullptr, nullptr, nullptr, gate_sig);

    // ---- MoE experts (reuse wbuf + inter) ----
    cvt_kernel<<<N_W13 / 1024, 256, 0, stream>>>(w13, w13_b);
    cvt_kernel<<<N_W2 / 1024, 256, 0, stream>>>(w2, w2_b);
    gemm_kernel<HID, 1><<<dim3(MINTER / BN, CAP / BM, NEXP), 256, lds_dual, stream>>>(
        xb, w13_b, inter, tok_list, counts, nullptr, nullptr);
    gemm_kernel<MINTER, 3><<<dim3(HID / BN, CAP / BM, NEXP), 256, lds_single, stream>>>(
        inter, w2_b, out, tok_list, counts, tok2w, nullptr);
}